// Round 2
// baseline (886.086 us; speedup 1.0000x reference)
//
#include <hip/hip_runtime.h>
#include <stdint.h>

#define BATCH 4096
#define DIM   2048
#define LROW  8191

typedef __attribute__((ext_vector_type(8))) short bf16x8;
typedef __attribute__((ext_vector_type(4))) float f32x4;
typedef __attribute__((ext_vector_type(4), aligned(4))) float f32x4u;  // 4B-aligned vector store

typedef __attribute__((address_space(1))) void gvoid;
typedef __attribute__((address_space(3))) void lvoid;
#define GLOAD16(g, l) __builtin_amdgcn_global_load_lds((gvoid*)(g), (lvoid*)(l), 16, 0, 0)

// float -> bf16 round-to-nearest-even
__device__ __forceinline__ unsigned short f2bf(float f) {
    unsigned int u = __float_as_uint(f);
    return (unsigned short)((u + 0x7FFFu + ((u >> 16) & 1u)) >> 16);
}
__device__ __forceinline__ float bf2f(unsigned short s) {
    return __uint_as_float(((unsigned int)s) << 16);
}

// ---------------- conversion kernels ----------------

__global__ __launch_bounds__(256) void k_cvt8(const float* __restrict__ src,
                                              unsigned short* __restrict__ dst) {
    size_t i = ((size_t)blockIdx.x * 256 + threadIdx.x) * 8;
    float4 v0 = *(const float4*)(src + i);
    float4 v1 = *(const float4*)(src + i + 4);
    bf16x8 p;
    p[0] = (short)f2bf(v0.x); p[1] = (short)f2bf(v0.y);
    p[2] = (short)f2bf(v0.z); p[3] = (short)f2bf(v0.w);
    p[4] = (short)f2bf(v1.x); p[5] = (short)f2bf(v1.y);
    p[6] = (short)f2bf(v1.z); p[7] = (short)f2bf(v1.w);
    *(bf16x8*)(dst + i) = p;
}

// W [k][n] f32 -> WT [n][k] bf16
__global__ __launch_bounds__(256) void k_transpose_cvt(const float* __restrict__ W,
                                                       unsigned short* __restrict__ WT) {
    __shared__ unsigned short t[32][33];
    int n0 = blockIdx.x * 32, k0 = blockIdx.y * 32;
    int tx = threadIdx.x, ty = threadIdx.y;  // (32,8)
#pragma unroll
    for (int i = 0; i < 4; i++) {
        int k = ty + i * 8;
        t[k][tx] = f2bf(W[(size_t)(k0 + k) * DIM + n0 + tx]);
    }
    __syncthreads();
#pragma unroll
    for (int i = 0; i < 4; i++) {
        int r = ty + i * 8;
        WT[(size_t)(n0 + r) * DIM + k0 + tx] = t[tx][r];
    }
}

// ============ 256x256-tile, BK=64, 8-wave, 8-phase GEMM  (A[M,K]bf16 x B[N,K]bf16^T) ============
// LDS ring: 8 half-tile slots x 16KB. Half-tile = [256 rows][32 k] bf16 (64B rows),
// st_16x32 swizzle (byte ^= ((byte>>9)&1)<<5) applied via pre-swizzled global source +
// swizzled ds_read address (both-sides involution).
// Half-tile order per K-tile t: ht=4t+{0:B-k0, 1:A-k0, 2:B-k1, 3:A-k1}; slot = ht&7.
// Phase p stages ht=p+6; slot(ht) was last read at phase ht+1 => overwrite at ht+2 is safe.
// vmcnt(6) once per K-tile (3 half-tiles in flight); vmcnt(0) only for last two tiles.
// EPI 0: H=bf16(acc+bias) + column sum/sumsq atomics   (GEMM1)
// EPI 1: G=bf16(acc+bias) + row sum-of-squares atomics (GEMM2)
// EPI 2: unified grams on stacked G[8192,2048]: upper-tri of 32x32 blocks (528).
//        value = acc * inv[i] * inv[j] / T. Fast path (no diag crossing): float4
//        nontemporal stores — mirror direct from regs, normal via 16x16 LDS transpose.
template <int EPI>
__global__ __launch_bounds__(512, 2) void k_g256(const short* __restrict__ A_,
                                                 const short* __restrict__ B_,
                                                 void* __restrict__ out0,
                                                 void* __restrict__ out1,
                                                 const float* __restrict__ bias,
                                                 float* __restrict__ st0,
                                                 float* __restrict__ st1,
                                                 const float* __restrict__ Tptr,
                                                 int K) {
    __shared__ __align__(16) char smem[131072];  // 8 slots x 16KB

    const int tid  = threadIdx.x;
    const int w    = tid >> 6;        // wave 0..7
    const int l    = tid & 63;
    const int lr   = l & 15;
    const int quad = l >> 4;
    const int wm   = w >> 2;          // 0..1  (M half: 128 rows)
    const int wn   = w & 3;           // 0..3  (N quarter: 64 cols)

    int m0, n0, bi = 0, bj = 0;
    if (EPI == 2) {
        int t = blockIdx.x;  // 0..527 upper-tri of 32x32
        while (t >= 32 - bi) { t -= 32 - bi; bi++; }
        bj = bi + t;
        m0 = bi * 256; n0 = bj * 256;
    } else {
        m0 = blockIdx.y * 256; n0 = blockIdx.x * 256;
    }

    const int NT = K >> 6;                 // K-tiles of 64
    const size_t rsb = (size_t)K * 2;      // row stride bytes

    // ---- staging constants: LDS dest linear (wave base + lane*16), source pre-swizzled
    const unsigned soff = (unsigned)((w * 1024 + l * 16) ^ (l & 32));  // bit5 ^= bit9
    const int rowS = soff >> 6;            // 0..127 (inst1 adds +128 rows)
    const int kbS  = soff & 63;
    const char* APan = (const char*)A_ + (size_t)(m0 + rowS) * rsb + kbS;
    const char* BPan = (const char*)B_ + (size_t)(n0 + rowS) * rsb + kbS;
    const size_t row128 = rsb << 7;        // 128 rows
    char* ldsS = smem + w * 1024;

    // ---- fragment-read bases (swizzled ds_read address)
    const int laneoff = (lr * 64 + quad * 16) ^ ((lr & 8) << 2);
    const char* ldsA = smem + wm * 8192 + laneoff;
    const char* ldsB = smem + wn * 4096 + laneoff;

    f32x4 acc[8][4] = {};
    bf16x8 aq[4], bq[4];

    auto STAGE = [&](int ht) {
        if (ht < 4 * NT) {
            const size_t koff = (size_t)((ht >> 2) * 128 + ((ht >> 1) & 1) * 64);
            char* d = ldsS + ((ht & 7) << 14);
            const char* s = (ht & 1) ? (APan + koff) : (BPan + koff);
            GLOAD16(s, d);
            GLOAD16(s + row128, d + 8192);
        }
    };

#define MM16(mh)                                                                     \
    _Pragma("unroll") for (int mi = 0; mi < 4; ++mi) {                               \
        _Pragma("unroll") for (int ni = 0; ni < 4; ++ni) {                           \
            acc[(mh) * 4 + mi][ni] = __builtin_amdgcn_mfma_f32_16x16x32_bf16(        \
                aq[mi], bq[ni], acc[(mh) * 4 + mi][ni], 0, 0, 0);                    \
        }                                                                            \
    }
#define BAR()   __builtin_amdgcn_s_barrier()
#define LGKM0() asm volatile("s_waitcnt lgkmcnt(0)" ::: "memory")

    // ---- prologue: 7 half-tiles (tile0 complete + 3 ahead)
    for (int ht = 0; ht < 7; ++ht) STAGE(ht);
    asm volatile("s_waitcnt vmcnt(6)" ::: "memory");
    BAR();

    int htn = 7;
    for (int t = 0; t < NT; ++t) {
        const int s0 = (t & 1) << 2;   // slots {s0..s0+3} = {B0,A0,B1,A1}
        // ---- phase 1: k-slice 0, m-half 0  (4 B-reads + 4 A-reads)
#pragma unroll
        for (int ni = 0; ni < 4; ++ni)
            bq[ni] = *(const bf16x8*)(ldsB + (s0 << 14) + ni * 1024);
#pragma unroll
        for (int mi = 0; mi < 4; ++mi)
            aq[mi] = *(const bf16x8*)(ldsA + ((s0 + 1) << 14) + mi * 1024);
        STAGE(htn); ++htn;
        BAR(); LGKM0();
        __builtin_amdgcn_s_setprio(1);
        MM16(0)
        __builtin_amdgcn_s_setprio(0);
        BAR();
        // ---- phase 2: k0, m-half 1 (4 A-reads, B reused from regs)
#pragma unroll
        for (int mi = 0; mi < 4; ++mi)
            aq[mi] = *(const bf16x8*)(ldsA + ((s0 + 1) << 14) + 4096 + mi * 1024);
        STAGE(htn); ++htn;
        BAR(); LGKM0();
        __builtin_amdgcn_s_setprio(1);
        MM16(1)
        __builtin_amdgcn_s_setprio(0);
        BAR();
        // ---- phase 3: k-slice 1, m-half 0
#pragma unroll
        for (int ni = 0; ni < 4; ++ni)
            bq[ni] = *(const bf16x8*)(ldsB + ((s0 + 2) << 14) + ni * 1024);
#pragma unroll
        for (int mi = 0; mi < 4; ++mi)
            aq[mi] = *(const bf16x8*)(ldsA + ((s0 + 3) << 14) + mi * 1024);
        STAGE(htn); ++htn;
        BAR(); LGKM0();
        __builtin_amdgcn_s_setprio(1);
        MM16(0)
        __builtin_amdgcn_s_setprio(0);
        BAR();
        // ---- phase 4: k1, m-half 1; counted vmcnt at tile boundary
#pragma unroll
        for (int mi = 0; mi < 4; ++mi)
            aq[mi] = *(const bf16x8*)(ldsA + ((s0 + 3) << 14) + 4096 + mi * 1024);
        STAGE(htn); ++htn;
        BAR(); LGKM0();
        __builtin_amdgcn_s_setprio(1);
        MM16(1)
        __builtin_amdgcn_s_setprio(0);
        if (t < NT - 2) { asm volatile("s_waitcnt vmcnt(6)" ::: "memory"); }
        else            { asm volatile("s_waitcnt vmcnt(0)" ::: "memory"); }
        BAR();
    }
#undef MM16

    // =============================== epilogues ===============================
    if (EPI == 0) {
        unsigned short* H = (unsigned short*)out0;
        const int half = m0 >> 12;
        float s[4] = {}, s2[4] = {};
#pragma unroll
        for (int ni = 0; ni < 4; ++ni) {
            const int col = n0 + wn * 64 + ni * 16 + lr;
            const float bv = bias[col];
#pragma unroll
            for (int mi = 0; mi < 8; ++mi) {
                const int row = m0 + wm * 128 + mi * 16 + quad * 4;
#pragma unroll
                for (int r = 0; r < 4; ++r) {
                    float v = acc[mi][ni][r] + bv;
                    H[(size_t)(row + r) * DIM + col] = f2bf(v);
                    s[ni] += v; s2[ni] += v * v;
                }
            }
        }
#pragma unroll
        for (int ni = 0; ni < 4; ++ni) {
            float a = s[ni], b = s2[ni];
            a += __shfl_xor(a, 16); b += __shfl_xor(b, 16);
            a += __shfl_xor(a, 32); b += __shfl_xor(b, 32);
            if (quad == 0) {
                const int col = n0 + wn * 64 + ni * 16 + lr;
                atomicAdd(&st0[half * DIM + col], a);
                atomicAdd(&st1[half * DIM + col], b);
            }
        }
    } else if (EPI == 1) {
        unsigned short* G = (unsigned short*)out0;
        float bv[4];
#pragma unroll
        for (int ni = 0; ni < 4; ++ni) bv[ni] = bias[n0 + wn * 64 + ni * 16 + lr];
#pragma unroll
        for (int mi = 0; mi < 8; ++mi) {
            const int rowb = m0 + wm * 128 + mi * 16 + quad * 4;
#pragma unroll
            for (int r = 0; r < 4; ++r) {
                const int row = rowb + r;
                float p = 0.f;
#pragma unroll
                for (int ni = 0; ni < 4; ++ni) {
                    const int col = n0 + wn * 64 + ni * 16 + lr;
                    float v = acc[mi][ni][r] + bv[ni];
                    G[(size_t)row * DIM + col] = f2bf(v);
                    p += v * v;
                }
                p += __shfl_xor(p, 1); p += __shfl_xor(p, 2);
                p += __shfl_xor(p, 4); p += __shfl_xor(p, 8);
                if (lr == 0) atomicAdd(&st0[row], p);
            }
        }
    } else {
        // unified grams on stacked G: bi,bj in [0,32), bj>=bi.
        const float invT = 1.0f / Tptr[0];
        const float* inv = st0;                 // rss (already rsqrt'd), stacked [8192]
        float* L1v = (float*)out0;
        float* L2v = (float*)out1;
        const bool crossm = (bi < 16) && (bj >= 16);
        const bool diagb  = (bi == bj);
        const bool strad  = crossm && (bj - 16 == bi);  // global i==j can occur
        float* Lw = (bi < 16) ? L1v : L2v;      // normal writes: rows live in bi's half
        float* Lm = (bj < 16) ? L1v : L2v;      // mirror writes: rows live in bj's half
        const int rbase = (bi < 16) ? 0 : 4096;
        const int cbase = (bj < 16) ? 0 : 4096;

        float ri[8][4], cj[4];
#pragma unroll
        for (int mi = 0; mi < 8; ++mi)
#pragma unroll
            for (int r = 0; r < 4; ++r)
                ri[mi][r] = inv[m0 + wm * 128 + mi * 16 + quad * 4 + r] * invT;
#pragma unroll
        for (int ni = 0; ni < 4; ++ni) cj[ni] = inv[n0 + wn * 64 + ni * 16 + lr];

        if (!diagb && !strad) {
            // ---- fast path: destination columns provably contiguous (no i==j in block)
            // mirror: lane holds (fixed row bl, 4 consecutive cols) directly.
            // normal: get (fixed row il, 4 consecutive cols) via per-wave 16x16 LDS transpose.
            const int off = crossm ? 4096 : 1;
            const int gtN = crossm ? (int)(bj - 16 > bi) : 1;  // jl > il uniform?
            const int gtM = crossm ? 1 - gtN : 0;              // al > bl uniform?
            float* tsc = (float*)smem + w * 320;               // 16 x pitch-20 floats
#pragma unroll
            for (int mi = 0; mi < 8; ++mi) {
                const int I0l = m0 + wm * 128 + mi * 16 - rbase;
#pragma unroll
                for (int ni = 0; ni < 4; ++ni) {
                    const int J0l = n0 + wn * 64 + ni * 16 - cbase;
                    f32x4u mv;
#pragma unroll
                    for (int r = 0; r < 4; ++r) mv[r] = acc[mi][ni][r] * ri[mi][r] * cj[ni];
                    // mirror float4: row bl, cols dcm(al0..al0+3)
                    const int bl  = J0l + lr;
                    const int al0 = I0l + quad * 4;
                    __builtin_nontemporal_store(
                        mv, (f32x4u*)(Lm + (size_t)bl * LROW + off + al0 - gtM));
                    // transpose in LDS (within-wave), then normal float4
#pragma unroll
                    for (int r = 0; r < 4; ++r) tsc[(quad * 4 + r) * 20 + lr] = mv[r];
                    f32x4u nv = *(const f32x4u*)(tsc + lr * 20 + quad * 4);
                    const int il  = I0l + lr;
                    const int jl0 = J0l + quad * 4;
                    __builtin_nontemporal_store(
                        nv, (f32x4u*)(Lw + (size_t)il * LROW + off + jl0 - gtN));
                }
            }
        } else {
            // ---- scalar path: diagonal (bi==bj) or cross-straddle (bj-16==bi) blocks
#pragma unroll
            for (int mi = 0; mi < 8; ++mi) {
                const int ib = m0 + wm * 128 + mi * 16 + quad * 4 - rbase;
#pragma unroll
                for (int ni = 0; ni < 4; ++ni) {
                    const int jl = n0 + wn * 64 + ni * 16 + lr - cbase;
#pragma unroll
                    for (int r = 0; r < 4; ++r) {
                        const int il = ib + r;
                        const float v = acc[mi][ni][r] * ri[mi][r] * cj[ni];
                        int dc;
                        if (crossm) {
                            dc = (jl == il) ? 0 : (4096 + jl - (jl > il));
                        } else {
                            if (jl == il) continue;
                            dc = 1 + jl - (jl > il);
                        }
                        __builtin_nontemporal_store(v, Lw + (size_t)il * LROW + dc);
                    }
                }
            }
            if (!diagb) {  // strad only: mirror via LDS transpose, scalar scatter
                float* tsc = (float*)smem + w * 320;
#pragma unroll
                for (int mi = 0; mi < 8; ++mi) {
                    const int al = m0 + wm * 128 + mi * 16 + lr - rbase;
#pragma unroll
                    for (int ni = 0; ni < 4; ++ni) {
                        const int J0 = n0 + wn * 64 + ni * 16 - cbase;
#pragma unroll
                        for (int r = 0; r < 4; ++r)
                            tsc[(quad * 4 + r) * 20 + lr] = acc[mi][ni][r] * ri[mi][r] * cj[ni];
#pragma unroll
                        for (int r = 0; r < 4; ++r) {
                            const int bl = J0 + quad * 4 + r;
                            const float tv = tsc[lr * 20 + quad * 4 + r];
                            const int dcm = (al == bl) ? 0 : (4096 + al - (al > bl));
                            __builtin_nontemporal_store(tv, Lm + (size_t)bl * LROW + dcm);
                        }
                    }
                }
            }
        }
    }
#undef BAR
#undef LGKM0
}

// ---------------- small elementwise kernels ----------------

__global__ __launch_bounds__(256) void k_bn_coef(float* __restrict__ musum,
                                                 float* __restrict__ sqsum,
                                                 const float* __restrict__ gamma,
                                                 const float* __restrict__ beta) {
    int i = blockIdx.x * 256 + threadIdx.x;  // 0..4095 = half*DIM+col
    int col = i & (DIM - 1);
    const float inv_n = 1.0f / 4096.0f;
    float mu = musum[i] * inv_n;
    float var = sqsum[i] * inv_n - mu * mu;
    float sc = rsqrtf(var + 1e-5f) * gamma[col];
    musum[i] = sc;
    sqsum[i] = beta[col] - mu * sc;
}

// Hn = relu(h*scale+shift), bf16 in-place
__global__ __launch_bounds__(256) void k_bn_apply(unsigned short* __restrict__ H,
                                                  const float* __restrict__ scale,
                                                  const float* __restrict__ shift) {
    size_t idx = ((size_t)blockIdx.x * 256 + threadIdx.x) * 8;
    int col = (int)(idx & (DIM - 1));
    int base = ((int)(idx >> 23)) * DIM + col;  // half*DIM + col
    bf16x8 hv = *(bf16x8*)(H + idx);
    float4 sc0 = *(const float4*)(scale + base);
    float4 sc1 = *(const float4*)(scale + base + 4);
    float4 sh0 = *(const float4*)(shift + base);
    float4 sh1 = *(const float4*)(shift + base + 4);
    float scl[8] = {sc0.x, sc0.y, sc0.z, sc0.w, sc1.x, sc1.y, sc1.z, sc1.w};
    float shf[8] = {sh0.x, sh0.y, sh0.z, sh0.w, sh1.x, sh1.y, sh1.z, sh1.w};
    bf16x8 o;
#pragma unroll
    for (int t = 0; t < 8; t++) {
        float x = bf2f((unsigned short)hv[t]);
        x = fmaxf(x * scl[t] + shf[t], 0.f);
        o[t] = (short)f2bf(x);
    }
    *(bf16x8*)(H + idx) = o;
}

__global__ __launch_bounds__(256) void k_rowinv(float* __restrict__ rss) {
    int i = blockIdx.x * 256 + threadIdx.x;  // 8192 rows
    rss[i] = rsqrtf(rss[i]);
}

// ---------------- launch ----------------

extern "C" void kernel_launch(void* const* d_in, const int* in_sizes, int n_in,
                              void* d_out, int out_size, void* d_ws, size_t ws_size,
                              hipStream_t stream) {
    const float* x1    = (const float*)d_in[0];
    const float* x2    = (const float*)d_in[1];
    const float* W1    = (const float*)d_in[2];
    const float* b1    = (const float*)d_in[3];
    const float* gamma = (const float*)d_in[4];
    const float* beta  = (const float*)d_in[5];
    const float* W2    = (const float*)d_in[6];
    const float* b2    = (const float*)d_in[7];
    const float* Tp    = (const float*)d_in[9];
    float* out = (float*)d_out;

    char* ws = (char*)d_ws;
    unsigned short* R1  = (unsigned short*)ws;                       // 32MB: Xb, then G
    unsigned short* R3  = (unsigned short*)(ws + (32ull << 20));     // 32MB: H/Hn
    unsigned short* W1T = (unsigned short*)(ws + (64ull << 20));     // 8MB
    unsigned short* W2T = (unsigned short*)(ws + (72ull << 20));     // 8MB
    float* musum = (float*)(ws + (80ull << 20));                     // [2][2048]
    float* sqsum = musum + 2 * DIM;                                  // [2][2048]
    float* rss   = sqsum + 2 * DIM;                                  // [8192]

    // zero the stat accumulators (ws is poisoned each call)
    hipMemsetAsync(musum, 0, (4 * DIM + 8192) * sizeof(float), stream);

    // 1. convert inputs
    k_cvt8<<<4096, 256, 0, stream>>>(x1, R1);
    k_cvt8<<<4096, 256, 0, stream>>>(x2, R1 + (size_t)BATCH * DIM);
    k_transpose_cvt<<<dim3(64, 64), dim3(32, 8), 0, stream>>>(W1, W1T);
    k_transpose_cvt<<<dim3(64, 64), dim3(32, 8), 0, stream>>>(W2, W2T);

    // 2. h = X @ W1 + b1 (bf16 out + fused column stats); 256 blocks = 1/CU
    k_g256<0><<<dim3(8, 32), 512, 0, stream>>>((const short*)R1, (const short*)W1T,
                                               R3, nullptr, b1, musum, sqsum, nullptr, DIM);
    // 3. BN coef + apply + ReLU (in-place on H)
    k_bn_coef<<<16, 256, 0, stream>>>(musum, sqsum, gamma, beta);
    k_bn_apply<<<8192, 256, 0, stream>>>(R3, musum, sqsum);

    // 4. g = Hn @ W2 + b2 (bf16 out + fused row sum-of-squares)
    k_g256<1><<<dim3(8, 32), 512, 0, stream>>>((const short*)R3, (const short*)W2T,
                                               R1, nullptr, b2, rss, nullptr, nullptr, DIM);
    // 5. inv row norms (normalization folded into gram epilogue — no q materialization)
    k_rowinv<<<32, 256, 0, stream>>>(rss);

    // 6. unified grams on stacked G: upper-tri of 32x32 256-blocks = 528
    float* L1 = out;
    float* L2 = out + (size_t)BATCH * LROW;
    k_g256<2><<<dim3(528, 1), 512, 0, stream>>>((const short*)R1, (const short*)R1,
                                                L1, L2, nullptr, rss, nullptr, Tp, DIM);

    // 7. labels = zeros
    hipMemsetAsync(out + (size_t)2 * BATCH * LROW, 0, BATCH * sizeof(int), stream);
}

// Round 4
// 755.499 us; speedup vs baseline: 1.1728x; 1.1728x over previous
//
#include <hip/hip_runtime.h>
#include <stdint.h>

#define BATCH 4096
#define DIM   2048
#define LROW  8191

typedef __attribute__((ext_vector_type(8))) short bf16x8;
typedef __attribute__((ext_vector_type(4))) float f32x4;
typedef __attribute__((ext_vector_type(4), aligned(4))) float f32x4u;  // 4B-aligned vector store

typedef __attribute__((address_space(1))) void gvoid;
typedef __attribute__((address_space(3))) void lvoid;
#define GLOAD16(g, l) __builtin_amdgcn_global_load_lds((gvoid*)(g), (lvoid*)(l), 16, 0, 0)

// float -> bf16 round-to-nearest-even
__device__ __forceinline__ unsigned short f2bf(float f) {
    unsigned int u = __float_as_uint(f);
    return (unsigned short)((u + 0x7FFFu + ((u >> 16) & 1u)) >> 16);
}
__device__ __forceinline__ float bf2f(unsigned short s) {
    return __uint_as_float(((unsigned int)s) << 16);
}

// ---------------- conversion kernels ----------------

__global__ __launch_bounds__(256) void k_cvt8(const float* __restrict__ src,
                                              unsigned short* __restrict__ dst) {
    size_t i = ((size_t)blockIdx.x * 256 + threadIdx.x) * 8;
    float4 v0 = *(const float4*)(src + i);
    float4 v1 = *(const float4*)(src + i + 4);
    bf16x8 p;
    p[0] = (short)f2bf(v0.x); p[1] = (short)f2bf(v0.y);
    p[2] = (short)f2bf(v0.z); p[3] = (short)f2bf(v0.w);
    p[4] = (short)f2bf(v1.x); p[5] = (short)f2bf(v1.y);
    p[6] = (short)f2bf(v1.z); p[7] = (short)f2bf(v1.w);
    *(bf16x8*)(dst + i) = p;
}

// W [k][n] f32 -> WT [n][k] bf16
__global__ __launch_bounds__(256) void k_transpose_cvt(const float* __restrict__ W,
                                                       unsigned short* __restrict__ WT) {
    __shared__ unsigned short t[32][33];
    int n0 = blockIdx.x * 32, k0 = blockIdx.y * 32;
    int tx = threadIdx.x, ty = threadIdx.y;  // (32,8)
#pragma unroll
    for (int i = 0; i < 4; i++) {
        int k = ty + i * 8;
        t[k][tx] = f2bf(W[(size_t)(k0 + k) * DIM + n0 + tx]);
    }
    __syncthreads();
#pragma unroll
    for (int i = 0; i < 4; i++) {
        int r = ty + i * 8;
        WT[(size_t)(n0 + r) * DIM + k0 + tx] = t[tx][r];
    }
}

// ============ 256x256-tile, BK=64, 8-wave, 8-phase GEMM  (A[M,K]bf16 x B[N,K]bf16^T) ============
// Main loop: verified 8-phase schedule (unchanged since round 1).
// EPI 0: H=bf16(acc+bias) + column sum/sumsq atomics   (GEMM1)
// EPI 1: G=bf16(acc+bias) + row sum-of-squares atomics (GEMM2)
// EPI 2: grams on stacked G[8192,2048], upper-tri of 32x32 blocks (528, XCD-swizzled);
//        value = acc * inv_i * inv_j / T. Fast path: f32x4 CACHED stores (nontemporal
//        removed — round-2 post-mortem: nt caused write-drain + 1.35x amplification).
template <int EPI>
__global__ __launch_bounds__(512, 2) void k_g256(const short* __restrict__ A_,
                                                 const short* __restrict__ B_,
                                                 void* __restrict__ out0,
                                                 void* __restrict__ out1,
                                                 const float* __restrict__ bias,
                                                 float* __restrict__ st0,
                                                 float* __restrict__ st1,
                                                 const float* __restrict__ Tptr,
                                                 int K) {
    __shared__ __align__(16) char smem[131072];  // 8 slots x 16KB

    const int tid  = threadIdx.x;
    const int w    = tid >> 6;        // wave 0..7
    const int l    = tid & 63;
    const int lr   = l & 15;
    const int quad = l >> 4;
    const int wm   = w >> 2;          // 0..1  (M half: 128 rows)
    const int wn   = w & 3;           // 0..3  (N quarter: 64 cols)

    int m0, n0, bi = 0, bj = 0;
    if (EPI == 2) {
        int t = blockIdx.x;  // 0..527 upper-tri of 32x32
        t = (t & 7) * 66 + (t >> 3);  // bijective XCD swizzle (528 = 8*66)
        while (t >= 32 - bi) { t -= 32 - bi; bi++; }
        bj = bi + t;
        m0 = bi * 256; n0 = bj * 256;
    } else {
        m0 = blockIdx.y * 256; n0 = blockIdx.x * 256;
    }

    const int NT = K >> 6;                 // K-tiles of 64
    const size_t rsb = (size_t)K * 2;      // row stride bytes

    // ---- staging constants: LDS dest linear (wave base + lane*16), source pre-swizzled
    const unsigned soff = (unsigned)((w * 1024 + l * 16) ^ (l & 32));  // bit5 ^= bit9
    const int rowS = soff >> 6;            // 0..127 (inst1 adds +128 rows)
    const int kbS  = soff & 63;
    const char* APan = (const char*)A_ + (size_t)(m0 + rowS) * rsb + kbS;
    const char* BPan = (const char*)B_ + (size_t)(n0 + rowS) * rsb + kbS;
    const size_t row128 = rsb << 7;        // 128 rows
    char* ldsS = smem + w * 1024;

    // ---- fragment-read bases (swizzled ds_read address)
    const int laneoff = (lr * 64 + quad * 16) ^ ((lr & 8) << 2);
    const char* ldsA = smem + wm * 8192 + laneoff;
    const char* ldsB = smem + wn * 4096 + laneoff;

    f32x4 acc[8][4] = {};
    bf16x8 aq[4], bq[4];

    auto STAGE = [&](int ht) {
        if (ht < 4 * NT) {
            const size_t koff = (size_t)((ht >> 2) * 128 + ((ht >> 1) & 1) * 64);
            char* d = ldsS + ((ht & 7) << 14);
            const char* s = (ht & 1) ? (APan + koff) : (BPan + koff);
            GLOAD16(s, d);
            GLOAD16(s + row128, d + 8192);
        }
    };

#define MM16(mh)                                                                     \
    _Pragma("unroll") for (int mi = 0; mi < 4; ++mi) {                               \
        _Pragma("unroll") for (int ni = 0; ni < 4; ++ni) {                           \
            acc[(mh) * 4 + mi][ni] = __builtin_amdgcn_mfma_f32_16x16x32_bf16(        \
                aq[mi], bq[ni], acc[(mh) * 4 + mi][ni], 0, 0, 0);                    \
        }                                                                            \
    }
#define BAR()   __builtin_amdgcn_s_barrier()
#define LGKM0() asm volatile("s_waitcnt lgkmcnt(0)" ::: "memory")

    // ---- prologue: 7 half-tiles (tile0 complete + 3 ahead)
    for (int ht = 0; ht < 7; ++ht) STAGE(ht);
    asm volatile("s_waitcnt vmcnt(6)" ::: "memory");
    BAR();

    int htn = 7;
    for (int t = 0; t < NT; ++t) {
        const int s0 = (t & 1) << 2;   // slots {s0..s0+3} = {B0,A0,B1,A1}
        // ---- phase 1: k-slice 0, m-half 0  (4 B-reads + 4 A-reads)
#pragma unroll
        for (int ni = 0; ni < 4; ++ni)
            bq[ni] = *(const bf16x8*)(ldsB + (s0 << 14) + ni * 1024);
#pragma unroll
        for (int mi = 0; mi < 4; ++mi)
            aq[mi] = *(const bf16x8*)(ldsA + ((s0 + 1) << 14) + mi * 1024);
        STAGE(htn); ++htn;
        BAR(); LGKM0();
        __builtin_amdgcn_s_setprio(1);
        MM16(0)
        __builtin_amdgcn_s_setprio(0);
        BAR();
        // ---- phase 2: k0, m-half 1 (4 A-reads, B reused from regs)
#pragma unroll
        for (int mi = 0; mi < 4; ++mi)
            aq[mi] = *(const bf16x8*)(ldsA + ((s0 + 1) << 14) + 4096 + mi * 1024);
        STAGE(htn); ++htn;
        BAR(); LGKM0();
        __builtin_amdgcn_s_setprio(1);
        MM16(1)
        __builtin_amdgcn_s_setprio(0);
        BAR();
        // ---- phase 3: k-slice 1, m-half 0
#pragma unroll
        for (int ni = 0; ni < 4; ++ni)
            bq[ni] = *(const bf16x8*)(ldsB + ((s0 + 2) << 14) + ni * 1024);
#pragma unroll
        for (int mi = 0; mi < 4; ++mi)
            aq[mi] = *(const bf16x8*)(ldsA + ((s0 + 3) << 14) + mi * 1024);
        STAGE(htn); ++htn;
        BAR(); LGKM0();
        __builtin_amdgcn_s_setprio(1);
        MM16(0)
        __builtin_amdgcn_s_setprio(0);
        BAR();
        // ---- phase 4: k1, m-half 1; counted vmcnt at tile boundary
#pragma unroll
        for (int mi = 0; mi < 4; ++mi)
            aq[mi] = *(const bf16x8*)(ldsA + ((s0 + 3) << 14) + 4096 + mi * 1024);
        STAGE(htn); ++htn;
        BAR(); LGKM0();
        __builtin_amdgcn_s_setprio(1);
        MM16(1)
        __builtin_amdgcn_s_setprio(0);
        if (t < NT - 2) { asm volatile("s_waitcnt vmcnt(6)" ::: "memory"); }
        else            { asm volatile("s_waitcnt vmcnt(0)" ::: "memory"); }
        BAR();
    }
#undef MM16

    // =============================== epilogues ===============================
    if (EPI == 0) {
        unsigned short* H = (unsigned short*)out0;
        const int half = m0 >> 12;
        float s[4] = {}, s2[4] = {};
#pragma unroll
        for (int ni = 0; ni < 4; ++ni) {
            const int col = n0 + wn * 64 + ni * 16 + lr;
            const float bv = bias[col];
#pragma unroll
            for (int mi = 0; mi < 8; ++mi) {
                const int row = m0 + wm * 128 + mi * 16 + quad * 4;
#pragma unroll
                for (int r = 0; r < 4; ++r) {
                    float v = acc[mi][ni][r] + bv;
                    H[(size_t)(row + r) * DIM + col] = f2bf(v);
                    s[ni] += v; s2[ni] += v * v;
                }
            }
        }
#pragma unroll
        for (int ni = 0; ni < 4; ++ni) {
            float a = s[ni], b = s2[ni];
            a += __shfl_xor(a, 16); b += __shfl_xor(b, 16);
            a += __shfl_xor(a, 32); b += __shfl_xor(b, 32);
            if (quad == 0) {
                const int col = n0 + wn * 64 + ni * 16 + lr;
                atomicAdd(&st0[half * DIM + col], a);
                atomicAdd(&st1[half * DIM + col], b);
            }
        }
    } else if (EPI == 1) {
        unsigned short* G = (unsigned short*)out0;
        float bv[4];
#pragma unroll
        for (int ni = 0; ni < 4; ++ni) bv[ni] = bias[n0 + wn * 64 + ni * 16 + lr];
#pragma unroll
        for (int mi = 0; mi < 8; ++mi) {
            const int rowb = m0 + wm * 128 + mi * 16 + quad * 4;
#pragma unroll
            for (int r = 0; r < 4; ++r) {
                const int row = rowb + r;
                float p = 0.f;
#pragma unroll
                for (int ni = 0; ni < 4; ++ni) {
                    const int col = n0 + wn * 64 + ni * 16 + lr;
                    float v = acc[mi][ni][r] + bv[ni];
                    G[(size_t)row * DIM + col] = f2bf(v);
                    p += v * v;
                }
                p += __shfl_xor(p, 1); p += __shfl_xor(p, 2);
                p += __shfl_xor(p, 4); p += __shfl_xor(p, 8);
                if (lr == 0) atomicAdd(&st0[row], p);
            }
        }
    } else {
        // unified grams on stacked G: bi,bj in [0,32), bj>=bi.
        const float invT = 1.0f / Tptr[0];
        const float* inv = st0;                 // rss (already rsqrt'd), stacked [8192]
        float* L1v = (float*)out0;
        float* L2v = (float*)out1;
        const bool crossm = (bi < 16) && (bj >= 16);
        const bool diagb  = (bi == bj);
        const bool strad  = crossm && (bj - 16 == bi);  // global i==j can occur
        float* Lw = (bi < 16) ? L1v : L2v;      // normal writes: rows live in bi's half
        float* Lm = (bj < 16) ? L1v : L2v;      // mirror writes: rows live in bj's half
        const int rbase = (bi < 16) ? 0 : 4096;
        const int cbase = (bj < 16) ? 0 : 4096;

        float ri[8][4], cj[4];
#pragma unroll
        for (int mi = 0; mi < 8; ++mi)
#pragma unroll
            for (int r = 0; r < 4; ++r)
                ri[mi][r] = inv[m0 + wm * 128 + mi * 16 + quad * 4 + r] * invT;
#pragma unroll
        for (int ni = 0; ni < 4; ++ni) cj[ni] = inv[n0 + wn * 64 + ni * 16 + lr];

        if (!diagb && !strad) {
            // ---- fast path: destination columns provably contiguous (no i==j in block)
            // mirror: lane holds (fixed row bl, 4 consecutive cols) directly.
            // normal: get (fixed row il, 4 consecutive cols) via per-wave 16x16 LDS transpose.
            const int off = crossm ? 4096 : 1;
            const int gtN = crossm ? (int)(bj - 16 > bi) : 1;  // jl > il uniform?
            const int gtM = crossm ? 1 - gtN : 0;              // al > bl uniform?
            float* tsc = (float*)smem + w * 320;               // 16 x pitch-20 floats
#pragma unroll
            for (int mi = 0; mi < 8; ++mi) {
                const int I0l = m0 + wm * 128 + mi * 16 - rbase;
#pragma unroll
                for (int ni = 0; ni < 4; ++ni) {
                    const int J0l = n0 + wn * 64 + ni * 16 - cbase;
                    f32x4u mv;
#pragma unroll
                    for (int r = 0; r < 4; ++r) mv[r] = acc[mi][ni][r] * ri[mi][r] * cj[ni];
                    // mirror float4: row bl, cols dcm(al0..al0+3)  [cached store]
                    const int bl  = J0l + lr;
                    const int al0 = I0l + quad * 4;
                    *(f32x4u*)(Lm + (size_t)bl * LROW + off + al0 - gtM) = mv;
                    // transpose in LDS (within-wave), then normal float4 [cached store]
#pragma unroll
                    for (int r = 0; r < 4; ++r) tsc[(quad * 4 + r) * 20 + lr] = mv[r];
                    f32x4u nv = *(const f32x4u*)(tsc + lr * 20 + quad * 4);
                    const int il  = I0l + lr;
                    const int jl0 = J0l + quad * 4;
                    *(f32x4u*)(Lw + (size_t)il * LROW + off + jl0 - gtN) = nv;
                }
            }
        } else {
            // ---- scalar path: diagonal (bi==bj) or cross-straddle (bj-16==bi) blocks
#pragma unroll
            for (int mi = 0; mi < 8; ++mi) {
                const int ib = m0 + wm * 128 + mi * 16 + quad * 4 - rbase;
#pragma unroll
                for (int ni = 0; ni < 4; ++ni) {
                    const int jl = n0 + wn * 64 + ni * 16 + lr - cbase;
#pragma unroll
                    for (int r = 0; r < 4; ++r) {
                        const int il = ib + r;
                        const float v = acc[mi][ni][r] * ri[mi][r] * cj[ni];
                        int dc;
                        if (crossm) {
                            dc = (jl == il) ? 0 : (4096 + jl - (jl > il));
                        } else {
                            if (jl == il) continue;
                            dc = 1 + jl - (jl > il);
                        }
                        Lw[(size_t)il * LROW + dc] = v;
                    }
                }
            }
            if (!diagb) {  // strad only: mirror via LDS transpose, scalar scatter
                float* tsc = (float*)smem + w * 320;
#pragma unroll
                for (int mi = 0; mi < 8; ++mi) {
                    const int al = m0 + wm * 128 + mi * 16 + lr - rbase;
#pragma unroll
                    for (int ni = 0; ni < 4; ++ni) {
                        const int J0 = n0 + wn * 64 + ni * 16 - cbase;
#pragma unroll
                        for (int r = 0; r < 4; ++r)
                            tsc[(quad * 4 + r) * 20 + lr] = acc[mi][ni][r] * ri[mi][r] * cj[ni];
#pragma unroll
                        for (int r = 0; r < 4; ++r) {
                            const int bl = J0 + quad * 4 + r;
                            const float tv = tsc[lr * 20 + quad * 4 + r];
                            const int dcm = (al == bl) ? 0 : (4096 + al - (al > bl));
                            Lm[(size_t)bl * LROW + dcm] = tv;
                        }
                    }
                }
            }
        }
    }
#undef BAR
#undef LGKM0
}

// ---------------- small elementwise kernels ----------------

__global__ __launch_bounds__(256) void k_bn_coef(float* __restrict__ musum,
                                                 float* __restrict__ sqsum,
                                                 const float* __restrict__ gamma,
                                                 const float* __restrict__ beta) {
    int i = blockIdx.x * 256 + threadIdx.x;  // 0..4095 = half*DIM+col
    int col = i & (DIM - 1);
    const float inv_n = 1.0f / 4096.0f;
    float mu = musum[i] * inv_n;
    float var = sqsum[i] * inv_n - mu * mu;
    float sc = rsqrtf(var + 1e-5f) * gamma[col];
    musum[i] = sc;
    sqsum[i] = beta[col] - mu * sc;
}

// Hn = relu(h*scale+shift), bf16 in-place
__global__ __launch_bounds__(256) void k_bn_apply(unsigned short* __restrict__ H,
                                                  const float* __restrict__ scale,
                                                  const float* __restrict__ shift) {
    size_t idx = ((size_t)blockIdx.x * 256 + threadIdx.x) * 8;
    int col = (int)(idx & (DIM - 1));
    int base = ((int)(idx >> 23)) * DIM + col;  // half*DIM + col
    bf16x8 hv = *(bf16x8*)(H + idx);
    float4 sc0 = *(const float4*)(scale + base);
    float4 sc1 = *(const float4*)(scale + base + 4);
    float4 sh0 = *(const float4*)(shift + base);
    float4 sh1 = *(const float4*)(shift + base + 4);
    float scl[8] = {sc0.x, sc0.y, sc0.z, sc0.w, sc1.x, sc1.y, sc1.z, sc1.w};
    float shf[8] = {sh0.x, sh0.y, sh0.z, sh0.w, sh1.x, sh1.y, sh1.z, sh1.w};
    bf16x8 o;
#pragma unroll
    for (int t = 0; t < 8; t++) {
        float x = bf2f((unsigned short)hv[t]);
        x = fmaxf(x * scl[t] + shf[t], 0.f);
        o[t] = (short)f2bf(x);
    }
    *(bf16x8*)(H + idx) = o;
}

__global__ __launch_bounds__(256) void k_rowinv(float* __restrict__ rss) {
    int i = blockIdx.x * 256 + threadIdx.x;  // 8192 rows
    rss[i] = rsqrtf(rss[i]);
}

// ---------------- launch ----------------

extern "C" void kernel_launch(void* const* d_in, const int* in_sizes, int n_in,
                              void* d_out, int out_size, void* d_ws, size_t ws_size,
                              hipStream_t stream) {
    const float* x1    = (const float*)d_in[0];
    const float* x2    = (const float*)d_in[1];
    const float* W1    = (const float*)d_in[2];
    const float* b1    = (const float*)d_in[3];
    const float* gamma = (const float*)d_in[4];
    const float* beta  = (const float*)d_in[5];
    const float* W2    = (const float*)d_in[6];
    const float* b2    = (const float*)d_in[7];
    const float* Tp    = (const float*)d_in[9];
    float* out = (float*)d_out;

    char* ws = (char*)d_ws;
    unsigned short* R1  = (unsigned short*)ws;                       // 32MB: Xb, then G
    unsigned short* R3  = (unsigned short*)(ws + (32ull << 20));     // 32MB: H/Hn
    unsigned short* W1T = (unsigned short*)(ws + (64ull << 20));     // 8MB
    unsigned short* W2T = (unsigned short*)(ws + (72ull << 20));     // 8MB
    float* musum = (float*)(ws + (80ull << 20));                     // [2][2048]
    float* sqsum = musum + 2 * DIM;                                  // [2][2048]
    float* rss   = sqsum + 2 * DIM;                                  // [8192]

    // zero the stat accumulators (ws is poisoned each call)
    hipMemsetAsync(musum, 0, (4 * DIM + 8192) * sizeof(float), stream);

    // 1. convert inputs
    k_cvt8<<<4096, 256, 0, stream>>>(x1, R1);
    k_cvt8<<<4096, 256, 0, stream>>>(x2, R1 + (size_t)BATCH * DIM);
    k_transpose_cvt<<<dim3(64, 64), dim3(32, 8), 0, stream>>>(W1, W1T);
    k_transpose_cvt<<<dim3(64, 64), dim3(32, 8), 0, stream>>>(W2, W2T);

    // 2. h = X @ W1 + b1 (bf16 out + fused column stats); 256 blocks = 1/CU
    k_g256<0><<<dim3(8, 32), 512, 0, stream>>>((const short*)R1, (const short*)W1T,
                                               R3, nullptr, b1, musum, sqsum, nullptr, DIM);
    // 3. BN coef + apply + ReLU (in-place on H)
    k_bn_coef<<<16, 256, 0, stream>>>(musum, sqsum, gamma, beta);
    k_bn_apply<<<8192, 256, 0, stream>>>(R3, musum, sqsum);

    // 4. g = Hn @ W2 + b2 (bf16 out + fused row sum-of-squares)
    k_g256<1><<<dim3(8, 32), 512, 0, stream>>>((const short*)R3, (const short*)W2T,
                                               R1, nullptr, b2, rss, nullptr, nullptr, DIM);
    // 5. normalize: rss -> 1/sqrt(rss)
    k_rowinv<<<32, 256, 0, stream>>>(rss);

    // 6. unified grams on stacked G: upper-tri of 32x32 256-blocks = 528 (XCD-swizzled)
    float* L1 = out;
    float* L2 = out + (size_t)BATCH * LROW;
    k_g256<2><<<dim3(528, 1), 512, 0, stream>>>((const short*)R1, (const short*)R1,
                                                L1, L2, nullptr, rss, nullptr, Tp, DIM);

    // 7. labels = zeros
    hipMemsetAsync(out + (size_t)2 * BATCH * LROW, 0, BATCH * sizeof(int), stream);
}

// Round 5
// 729.371 us; speedup vs baseline: 1.2149x; 1.0358x over previous
//
#include <hip/hip_runtime.h>
#include <stdint.h>

#define BATCH 4096
#define DIM   2048
#define LROW  8191

typedef __attribute__((ext_vector_type(8))) short bf16x8;
typedef __attribute__((ext_vector_type(4))) float f32x4;

typedef __attribute__((address_space(1))) void gvoid;
typedef __attribute__((address_space(3))) void lvoid;
#define GLOAD16(g, l) __builtin_amdgcn_global_load_lds((gvoid*)(g), (lvoid*)(l), 16, 0, 0)

// float -> bf16 round-to-nearest-even
__device__ __forceinline__ unsigned short f2bf(float f) {
    unsigned int u = __float_as_uint(f);
    return (unsigned short)((u + 0x7FFFu + ((u >> 16) & 1u)) >> 16);
}
__device__ __forceinline__ float bf2f(unsigned short s) {
    return __uint_as_float(((unsigned int)s) << 16);
}

// ---------------- conversion kernels ----------------

__global__ __launch_bounds__(256) void k_cvt8(const float* __restrict__ src,
                                              unsigned short* __restrict__ dst) {
    size_t i = ((size_t)blockIdx.x * 256 + threadIdx.x) * 8;
    float4 v0 = *(const float4*)(src + i);
    float4 v1 = *(const float4*)(src + i + 4);
    bf16x8 p;
    p[0] = (short)f2bf(v0.x); p[1] = (short)f2bf(v0.y);
    p[2] = (short)f2bf(v0.z); p[3] = (short)f2bf(v0.w);
    p[4] = (short)f2bf(v1.x); p[5] = (short)f2bf(v1.y);
    p[6] = (short)f2bf(v1.z); p[7] = (short)f2bf(v1.w);
    *(bf16x8*)(dst + i) = p;
}

// W [k][n] f32 -> WT [n][k] bf16
__global__ __launch_bounds__(256) void k_transpose_cvt(const float* __restrict__ W,
                                                       unsigned short* __restrict__ WT) {
    __shared__ unsigned short t[32][33];
    int n0 = blockIdx.x * 32, k0 = blockIdx.y * 32;
    int tx = threadIdx.x, ty = threadIdx.y;  // (32,8)
#pragma unroll
    for (int i = 0; i < 4; i++) {
        int k = ty + i * 8;
        t[k][tx] = f2bf(W[(size_t)(k0 + k) * DIM + n0 + tx]);
    }
    __syncthreads();
#pragma unroll
    for (int i = 0; i < 4; i++) {
        int r = ty + i * 8;
        WT[(size_t)(n0 + r) * DIM + k0 + tx] = t[tx][r];
    }
}

// ============ 256x256-tile, BK=64, 8-wave, 8-phase GEMM  (A[M,K]bf16 x B[N,K]bf16^T) ============
// Round-5 phase micro-structure: STAGE issued first, then ds_reads; NO explicit lgkmcnt
// (compiler inserts fine-grained per-use waits); sched_barrier(0) pins the issue region
// above the leading s_barrier and the MFMA cluster above the trailing s_barrier (rule #18).
// Slot-overwrite safety: every ds_read is consumed by its own phase's MFMA, so reads
// complete before the trailing barrier; staging overwrites a slot >=1 full phase after
// its last read. vmcnt(6) once per K-tile; vmcnt(0) only for the last two tiles.
// EPI 0: H=bf16(acc+bias) + column sum/sumsq atomics   (GEMM1)
// EPI 1: G=bf16(acc+bias) + row sum-of-squares atomics (GEMM2)
// EPI 2: grams on stacked G[8192,2048], upper-tri of 32x32 blocks (528, XCD-swizzled);
//        scalar cached stores (round-1 proven path; f32x4 was a loss: LROW=8191 => 4B
//        alignment => line-straddle write amplification, r4 post-mortem).
template <int EPI>
__global__ __launch_bounds__(512, 2) void k_g256(const short* __restrict__ A_,
                                                 const short* __restrict__ B_,
                                                 void* __restrict__ out0,
                                                 void* __restrict__ out1,
                                                 const float* __restrict__ bias,
                                                 float* __restrict__ st0,
                                                 float* __restrict__ st1,
                                                 const float* __restrict__ Tptr,
                                                 int K) {
    __shared__ __align__(16) char smem[131072];  // 8 slots x 16KB

    const int tid  = threadIdx.x;
    const int w    = tid >> 6;        // wave 0..7
    const int l    = tid & 63;
    const int lr   = l & 15;
    const int quad = l >> 4;
    const int wm   = w >> 2;          // 0..1  (M half: 128 rows)
    const int wn   = w & 3;           // 0..3  (N quarter: 64 cols)

    int m0, n0, bi = 0, bj = 0;
    if (EPI == 2) {
        int t = blockIdx.x;  // 0..527 upper-tri of 32x32
        t = (t & 7) * 66 + (t >> 3);  // bijective XCD swizzle (528 = 8*66)
        while (t >= 32 - bi) { t -= 32 - bi; bi++; }
        bj = bi + t;
        m0 = bi * 256; n0 = bj * 256;
    } else {
        m0 = blockIdx.y * 256; n0 = blockIdx.x * 256;
    }

    const int NT = K >> 6;                 // K-tiles of 64
    const size_t rsb = (size_t)K * 2;      // row stride bytes

    // ---- staging constants: LDS dest linear (wave base + lane*16), source pre-swizzled
    const unsigned soff = (unsigned)((w * 1024 + l * 16) ^ (l & 32));  // bit5 ^= bit9
    const int rowS = soff >> 6;            // 0..127 (inst1 adds +128 rows)
    const int kbS  = soff & 63;
    const char* APan = (const char*)A_ + (size_t)(m0 + rowS) * rsb + kbS;
    const char* BPan = (const char*)B_ + (size_t)(n0 + rowS) * rsb + kbS;
    const size_t row128 = rsb << 7;        // 128 rows
    char* ldsS = smem + w * 1024;

    // ---- fragment-read bases (swizzled ds_read address)
    const int laneoff = (lr * 64 + quad * 16) ^ ((lr & 8) << 2);
    const char* ldsA = smem + wm * 8192 + laneoff;
    const char* ldsB = smem + wn * 4096 + laneoff;

    f32x4 acc[8][4] = {};
    bf16x8 aq[4], bq[4];

    auto STAGE = [&](int ht) {
        if (ht < 4 * NT) {
            const size_t koff = (size_t)((ht >> 2) * 128 + ((ht >> 1) & 1) * 64);
            char* d = ldsS + ((ht & 7) << 14);
            const char* s = (ht & 1) ? (APan + koff) : (BPan + koff);
            GLOAD16(s, d);
            GLOAD16(s + row128, d + 8192);
        }
    };

#define MM16(mh)                                                                     \
    _Pragma("unroll") for (int mi = 0; mi < 4; ++mi) {                               \
        _Pragma("unroll") for (int ni = 0; ni < 4; ++ni) {                           \
            acc[(mh) * 4 + mi][ni] = __builtin_amdgcn_mfma_f32_16x16x32_bf16(        \
                aq[mi], bq[ni], acc[(mh) * 4 + mi][ni], 0, 0, 0);                    \
        }                                                                            \
    }
#define BAR()  __builtin_amdgcn_s_barrier()
#define SBAR() __builtin_amdgcn_sched_barrier(0)

    // ---- prologue: 7 half-tiles (tile0 complete + 3 ahead)
    for (int ht = 0; ht < 7; ++ht) STAGE(ht);
    asm volatile("s_waitcnt vmcnt(6)" ::: "memory");
    BAR();

    int htn = 7;
    for (int t = 0; t < NT; ++t) {
        const int s0 = (t & 1) << 2;   // slots {s0..s0+3} = {B0,A0,B1,A1}
        // ---- phase 1: k-slice 0, m-half 0
        STAGE(htn); ++htn;
#pragma unroll
        for (int ni = 0; ni < 4; ++ni)
            bq[ni] = *(const bf16x8*)(ldsB + (s0 << 14) + ni * 1024);
#pragma unroll
        for (int mi = 0; mi < 4; ++mi)
            aq[mi] = *(const bf16x8*)(ldsA + ((s0 + 1) << 14) + mi * 1024);
        SBAR();
        BAR();
        __builtin_amdgcn_s_setprio(1);
        MM16(0)
        __builtin_amdgcn_s_setprio(0);
        SBAR();
        BAR();
        // ---- phase 2: k0, m-half 1 (B reused from regs)
        STAGE(htn); ++htn;
#pragma unroll
        for (int mi = 0; mi < 4; ++mi)
            aq[mi] = *(const bf16x8*)(ldsA + ((s0 + 1) << 14) + 4096 + mi * 1024);
        SBAR();
        BAR();
        __builtin_amdgcn_s_setprio(1);
        MM16(1)
        __builtin_amdgcn_s_setprio(0);
        SBAR();
        BAR();
        // ---- phase 3: k-slice 1, m-half 0
        STAGE(htn); ++htn;
#pragma unroll
        for (int ni = 0; ni < 4; ++ni)
            bq[ni] = *(const bf16x8*)(ldsB + ((s0 + 2) << 14) + ni * 1024);
#pragma unroll
        for (int mi = 0; mi < 4; ++mi)
            aq[mi] = *(const bf16x8*)(ldsA + ((s0 + 3) << 14) + mi * 1024);
        SBAR();
        BAR();
        __builtin_amdgcn_s_setprio(1);
        MM16(0)
        __builtin_amdgcn_s_setprio(0);
        SBAR();
        BAR();
        // ---- phase 4: k1, m-half 1; counted vmcnt at tile boundary
        STAGE(htn); ++htn;
#pragma unroll
        for (int mi = 0; mi < 4; ++mi)
            aq[mi] = *(const bf16x8*)(ldsA + ((s0 + 3) << 14) + 4096 + mi * 1024);
        SBAR();
        BAR();
        __builtin_amdgcn_s_setprio(1);
        MM16(1)
        __builtin_amdgcn_s_setprio(0);
        SBAR();
        if (t < NT - 2) { asm volatile("s_waitcnt vmcnt(6)" ::: "memory"); }
        else            { asm volatile("s_waitcnt vmcnt(0)" ::: "memory"); }
        BAR();
    }
#undef MM16

    // =============================== epilogues ===============================
    if (EPI == 0) {
        unsigned short* H = (unsigned short*)out0;
        const int half = m0 >> 12;
        float s[4] = {}, s2[4] = {};
#pragma unroll
        for (int ni = 0; ni < 4; ++ni) {
            const int col = n0 + wn * 64 + ni * 16 + lr;
            const float bv = bias[col];
#pragma unroll
            for (int mi = 0; mi < 8; ++mi) {
                const int row = m0 + wm * 128 + mi * 16 + quad * 4;
#pragma unroll
                for (int r = 0; r < 4; ++r) {
                    float v = acc[mi][ni][r] + bv;
                    H[(size_t)(row + r) * DIM + col] = f2bf(v);
                    s[ni] += v; s2[ni] += v * v;
                }
            }
        }
#pragma unroll
        for (int ni = 0; ni < 4; ++ni) {
            float a = s[ni], b = s2[ni];
            a += __shfl_xor(a, 16); b += __shfl_xor(b, 16);
            a += __shfl_xor(a, 32); b += __shfl_xor(b, 32);
            if (quad == 0) {
                const int col = n0 + wn * 64 + ni * 16 + lr;
                atomicAdd(&st0[half * DIM + col], a);
                atomicAdd(&st1[half * DIM + col], b);
            }
        }
    } else if (EPI == 1) {
        unsigned short* G = (unsigned short*)out0;
        float bv[4];
#pragma unroll
        for (int ni = 0; ni < 4; ++ni) bv[ni] = bias[n0 + wn * 64 + ni * 16 + lr];
#pragma unroll
        for (int mi = 0; mi < 8; ++mi) {
            const int rowb = m0 + wm * 128 + mi * 16 + quad * 4;
#pragma unroll
            for (int r = 0; r < 4; ++r) {
                const int row = rowb + r;
                float p = 0.f;
#pragma unroll
                for (int ni = 0; ni < 4; ++ni) {
                    const int col = n0 + wn * 64 + ni * 16 + lr;
                    float v = acc[mi][ni][r] + bv[ni];
                    G[(size_t)row * DIM + col] = f2bf(v);
                    p += v * v;
                }
                p += __shfl_xor(p, 1); p += __shfl_xor(p, 2);
                p += __shfl_xor(p, 4); p += __shfl_xor(p, 8);
                if (lr == 0) atomicAdd(&st0[row], p);
            }
        }
    } else {
        // unified grams on stacked G: bi,bj in [0,32), bj>=bi. Scalar cached stores.
        const float invT = 1.0f / Tptr[0];
        const float* inv = st0;                 // rss (already rsqrt'd), stacked [8192]
        float* L1v = (float*)out0;
        float* L2v = (float*)out1;
        const bool crossm = (bi < 16) && (bj >= 16);
        const bool diagb  = (bi == bj);
        float* Lw = (bi < 16) ? L1v : L2v;      // normal writes: rows live in bi's half
        float* Lm = (bj < 16) ? L1v : L2v;      // mirror writes: rows live in bj's half
        const int rbase = (bi < 16) ? 0 : 4096;
        const int cbase = (bj < 16) ? 0 : 4096;

        float ri[8][4], cj[4];
#pragma unroll
        for (int mi = 0; mi < 8; ++mi)
#pragma unroll
            for (int r = 0; r < 4; ++r)
                ri[mi][r] = inv[m0 + wm * 128 + mi * 16 + quad * 4 + r] * invT;
#pragma unroll
        for (int ni = 0; ni < 4; ++ni) cj[ni] = inv[n0 + wn * 64 + ni * 16 + lr];

        // normal writes (rows i from m-block)
#pragma unroll
        for (int mi = 0; mi < 8; ++mi) {
            const int ib = m0 + wm * 128 + mi * 16 + quad * 4 - rbase;
#pragma unroll
            for (int ni = 0; ni < 4; ++ni) {
                const int jl = n0 + wn * 64 + ni * 16 + lr - cbase;
#pragma unroll
                for (int r = 0; r < 4; ++r) {
                    const int il = ib + r;
                    const float v = acc[mi][ni][r] * ri[mi][r] * cj[ni];
                    int dc;
                    if (crossm) {
                        dc = (jl == il) ? 0 : (4096 + jl - (jl > il));
                    } else {
                        if (jl == il) continue;
                        dc = 1 + jl - (jl > il);
                    }
                    Lw[(size_t)il * LROW + dc] = v;
                }
            }
        }
        // mirror writes via per-wave 16x16 LDS transpose (exact same fp values)
        if (!diagb) {
            float* tsc = (float*)smem + w * 320;  // 16 rows x pitch 20
#pragma unroll
            for (int mi = 0; mi < 8; ++mi) {
                const int al = m0 + wm * 128 + mi * 16 + lr - rbase;  // orig row -> mirror col
#pragma unroll
                for (int ni = 0; ni < 4; ++ni) {
                    const int J0 = n0 + wn * 64 + ni * 16 - cbase;
#pragma unroll
                    for (int r = 0; r < 4; ++r)
                        tsc[(quad * 4 + r) * 20 + lr] = acc[mi][ni][r] * ri[mi][r] * cj[ni];
#pragma unroll
                    for (int r = 0; r < 4; ++r) {
                        const int bl = J0 + quad * 4 + r;             // orig col -> mirror row
                        const float tv = tsc[lr * 20 + quad * 4 + r];
                        int dcm;
                        if (crossm) dcm = (al == bl) ? 0 : (4096 + al - (al > bl));
                        else        dcm = 1 + al - (al > bl);         // al<bl here
                        Lm[(size_t)bl * LROW + dcm] = tv;
                    }
                }
            }
        }
    }
#undef BAR
#undef SBAR
}

// ---------------- small elementwise kernels ----------------

__global__ __launch_bounds__(256) void k_bn_coef(float* __restrict__ musum,
                                                 float* __restrict__ sqsum,
                                                 const float* __restrict__ gamma,
                                                 const float* __restrict__ beta) {
    int i = blockIdx.x * 256 + threadIdx.x;  // 0..4095 = half*DIM+col
    int col = i & (DIM - 1);
    const float inv_n = 1.0f / 4096.0f;
    float mu = musum[i] * inv_n;
    float var = sqsum[i] * inv_n - mu * mu;
    float sc = rsqrtf(var + 1e-5f) * gamma[col];
    musum[i] = sc;
    sqsum[i] = beta[col] - mu * sc;
}

// Hn = relu(h*scale+shift), bf16 in-place
__global__ __launch_bounds__(256) void k_bn_apply(unsigned short* __restrict__ H,
                                                  const float* __restrict__ scale,
                                                  const float* __restrict__ shift) {
    size_t idx = ((size_t)blockIdx.x * 256 + threadIdx.x) * 8;
    int col = (int)(idx & (DIM - 1));
    int base = ((int)(idx >> 23)) * DIM + col;  // half*DIM + col
    bf16x8 hv = *(bf16x8*)(H + idx);
    float4 sc0 = *(const float4*)(scale + base);
    float4 sc1 = *(const float4*)(scale + base + 4);
    float4 sh0 = *(const float4*)(shift + base);
    float4 sh1 = *(const float4*)(shift + base + 4);
    float scl[8] = {sc0.x, sc0.y, sc0.z, sc0.w, sc1.x, sc1.y, sc1.z, sc1.w};
    float shf[8] = {sh0.x, sh0.y, sh0.z, sh0.w, sh1.x, sh1.y, sh1.z, sh1.w};
    bf16x8 o;
#pragma unroll
    for (int t = 0; t < 8; t++) {
        float x = bf2f((unsigned short)hv[t]);
        x = fmaxf(x * scl[t] + shf[t], 0.f);
        o[t] = (short)f2bf(x);
    }
    *(bf16x8*)(H + idx) = o;
}

__global__ __launch_bounds__(256) void k_rowinv(float* __restrict__ rss) {
    int i = blockIdx.x * 256 + threadIdx.x;  // 8192 rows
    rss[i] = rsqrtf(rss[i]);
}

// ---------------- launch ----------------

extern "C" void kernel_launch(void* const* d_in, const int* in_sizes, int n_in,
                              void* d_out, int out_size, void* d_ws, size_t ws_size,
                              hipStream_t stream) {
    const float* x1    = (const float*)d_in[0];
    const float* x2    = (const float*)d_in[1];
    const float* W1    = (const float*)d_in[2];
    const float* b1    = (const float*)d_in[3];
    const float* gamma = (const float*)d_in[4];
    const float* beta  = (const float*)d_in[5];
    const float* W2    = (const float*)d_in[6];
    const float* b2    = (const float*)d_in[7];
    const float* Tp    = (const float*)d_in[9];
    float* out = (float*)d_out;

    char* ws = (char*)d_ws;
    unsigned short* R1  = (unsigned short*)ws;                       // 32MB: Xb, then G
    unsigned short* R3  = (unsigned short*)(ws + (32ull << 20));     // 32MB: H/Hn
    unsigned short* W1T = (unsigned short*)(ws + (64ull << 20));     // 8MB
    unsigned short* W2T = (unsigned short*)(ws + (72ull << 20));     // 8MB
    float* musum = (float*)(ws + (80ull << 20));                     // [2][2048]
    float* sqsum = musum + 2 * DIM;                                  // [2][2048]
    float* rss   = sqsum + 2 * DIM;                                  // [8192]

    // zero the stat accumulators (ws is poisoned each call)
    hipMemsetAsync(musum, 0, (4 * DIM + 8192) * sizeof(float), stream);

    // 1. convert inputs
    k_cvt8<<<4096, 256, 0, stream>>>(x1, R1);
    k_cvt8<<<4096, 256, 0, stream>>>(x2, R1 + (size_t)BATCH * DIM);
    k_transpose_cvt<<<dim3(64, 64), dim3(32, 8), 0, stream>>>(W1, W1T);
    k_transpose_cvt<<<dim3(64, 64), dim3(32, 8), 0, stream>>>(W2, W2T);

    // 2. h = X @ W1 + b1 (bf16 out + fused column stats); 256 blocks = 1/CU
    k_g256<0><<<dim3(8, 32), 512, 0, stream>>>((const short*)R1, (const short*)W1T,
                                               R3, nullptr, b1, musum, sqsum, nullptr, DIM);
    // 3. BN coef + apply + ReLU (in-place on H)
    k_bn_coef<<<16, 256, 0, stream>>>(musum, sqsum, gamma, beta);
    k_bn_apply<<<8192, 256, 0, stream>>>(R3, musum, sqsum);

    // 4. g = Hn @ W2 + b2 (bf16 out + fused row sum-of-squares)
    k_g256<1><<<dim3(8, 32), 512, 0, stream>>>((const short*)R3, (const short*)W2T,
                                               R1, nullptr, b2, rss, nullptr, nullptr, DIM);
    // 5. normalize: rss -> 1/sqrt(rss)
    k_rowinv<<<32, 256, 0, stream>>>(rss);

    // 6. unified grams on stacked G: upper-tri of 32x32 256-blocks = 528 (XCD-swizzled)
    float* L1 = out;
    float* L2 = out + (size_t)BATCH * LROW;
    k_g256<2><<<dim3(528, 1), 512, 0, stream>>>((const short*)R1, (const short*)R1,
                                                L1, L2, nullptr, rss, nullptr, Tp, DIM);

    // 7. labels = zeros
    hipMemsetAsync(out + (size_t)2 * BATCH * LROW, 0, BATCH * sizeof(int), stream);
}